// Round 6
// baseline (195.389 us; speedup 1.0000x reference)
//
#include <hip/hip_runtime.h>
#include <cstddef>

// DCT-II matrix (float32 cast of numpy's float64 values)
static constexpr float D8[8][8] = {
  { 0.35355339059327373f, 0.35355339059327373f, 0.35355339059327373f, 0.35355339059327373f,
    0.35355339059327373f, 0.35355339059327373f, 0.35355339059327373f, 0.35355339059327373f},
  { 0.4903926402016152f,  0.4157348061512726f,  0.27778511650980114f, 0.09754516100806417f,
   -0.09754516100806417f,-0.27778511650980114f,-0.4157348061512726f, -0.4903926402016152f},
  { 0.46193976625564337f, 0.19134171618254492f,-0.19134171618254492f,-0.46193976625564337f,
   -0.46193976625564337f,-0.19134171618254492f, 0.19134171618254492f, 0.46193976625564337f},
  { 0.4157348061512726f, -0.09754516100806417f,-0.4903926402016152f, -0.27778511650980114f,
    0.27778511650980114f, 0.4903926402016152f,  0.09754516100806417f,-0.4157348061512726f},
  { 0.35355339059327373f,-0.35355339059327373f,-0.35355339059327373f, 0.35355339059327373f,
    0.35355339059327373f,-0.35355339059327373f,-0.35355339059327373f, 0.35355339059327373f},
  { 0.27778511650980114f,-0.4903926402016152f,  0.09754516100806417f, 0.4157348061512726f,
   -0.4157348061512726f, -0.09754516100806417f, 0.4903926402016152f, -0.27778511650980114f},
  { 0.19134171618254492f,-0.46193976625564337f, 0.46193976625564337f,-0.19134171618254492f,
   -0.19134171618254492f, 0.46193976625564337f,-0.46193976625564337f, 0.19134171618254492f},
  { 0.09754516100806417f,-0.27778511650980114f, 0.4157348061512726f, -0.4903926402016152f,
    0.4903926402016152f, -0.4157348061512726f,  0.27778511650980114f,-0.09754516100806417f},
};

// Quality-95 quant tables: q = clamp(floor((base*10+50)/100), 1, 255)
static constexpr float QLt[8][8] = {
  {2,1,1,2,2,4,5,6},
  {1,1,1,2,3,6,6,6},
  {1,1,2,2,4,6,7,6},
  {1,2,2,3,5,9,8,6},
  {2,2,4,6,7,11,10,8},
  {2,4,6,6,8,10,11,9},
  {5,6,8,9,10,12,12,10},
  {7,9,10,10,11,10,10,10},
};
static constexpr float QCt[8][8] = {
  {2,2,2,5,10,10,10,10},
  {2,2,3,7,10,10,10,10},
  {2,3,6,10,10,10,10,10},
  {5,7,10,10,10,10,10,10},
  {10,10,10,10,10,10,10,10},
  {10,10,10,10,10,10,10,10},
  {10,10,10,10,10,10,10,10},
  {10,10,10,10,10,10,10,10},
};

static constexpr float C255  = (float)(1.0/255.0);  // fl(1/255): matches jnp's f32 divisor
static constexpr float RC255 = 1.0f / C255;         // correctly-rounded reciprocal (constexpr IEEE)

// Markstein exactly-rounded division by constant c with precomputed r = fl(1/c):
// bit-identical to IEEE x/c, 3 VALU ops.
__device__ __forceinline__ float exact_div(float x, float c, float r) {
  float q0 = x * r;
  float e  = fmaf(-c, q0, x);
  return fmaf(e, r, q0);
}

// u[k] = sum_j D8[k][j] * x[j]
__device__ __forceinline__ void dct8(const float x[8], float u[8]) {
  #pragma unroll
  for (int k = 0; k < 8; ++k) {
    float a = D8[k][0] * x[0];
    #pragma unroll
    for (int j = 1; j < 8; ++j) a += D8[k][j] * x[j];
    u[k] = a;
  }
}

// u[j] = sum_m x[m] * D8[m][j]
__device__ __forceinline__ void idct8(const float x[8], float u[8]) {
  #pragma unroll
  for (int j = 0; j < 8; ++j) {
    float a = x[0] * D8[0][j];
    #pragma unroll
    for (int m = 1; m < 8; ++m) a += x[m] * D8[m][j];
    u[j] = a;
  }
}

// THREE interleaved in-register 8x8 transposes across an aligned 8-lane group.
// Branch-free (round-1 lesson: divergent private-array stores -> scratch).
__device__ __forceinline__ void xpose3(float a[8], float b[8], float c[8], int lane) {
  #pragma unroll
  for (int s = 1; s < 8; s <<= 1) {
    const bool hi = (lane & s) != 0;
    #pragma unroll
    for (int r0 = 0; r0 < 8; ++r0) {
      if (r0 & s) continue;            // compile-time skip
      const int r1 = r0 | s;
      const float a0 = a[r0], a1 = a[r1];
      const float b0 = b[r0], b1 = b[r1];
      const float c0 = c[r0], c1 = c[r1];
      const float ga = __shfl_xor(hi ? a0 : a1, s, 64);
      const float gb = __shfl_xor(hi ? b0 : b1, s, 64);
      const float gc = __shfl_xor(hi ? c0 : c1, s, 64);
      a[r0] = hi ? ga : a0;  a[r1] = hi ? a1 : ga;
      b[r0] = hi ? gb : b0;  b[r1] = hi ? b1 : gb;
      c[r0] = hi ? gc : c0;  c[r1] = hi ? c1 : gc;
    }
  }
}

__device__ __forceinline__ void quant8(float v[8], const float* QT, const float* RQ) {
  float4 Q0 = *(const float4*)&QT[0];
  float4 Q1 = *(const float4*)&QT[4];
  float4 R0 = *(const float4*)&RQ[0];
  float4 R1 = *(const float4*)&RQ[4];
  float qv[8] = {Q0.x,Q0.y,Q0.z,Q0.w,Q1.x,Q1.y,Q1.z,Q1.w};
  float rv[8] = {R0.x,R0.y,R0.z,R0.w,R1.x,R1.y,R1.z,R1.w};
  #pragma unroll
  for (int m = 0; m < 8; ++m)
    v[m] = rintf(exact_div(v[m], qv[m], rv[m])) * qv[m];
}

// Workgroup barrier WITHOUT the vmcnt(0) drain hipcc emits for __syncthreads.
// Orders LDS (lgkmcnt covers DS ops) across the WG while leaving global
// loads/stores in flight — required for the cross-tile register prefetch.
// The "memory" clobber also pins issued loads above the barrier so the
// compiler cannot sink/serialize the prefetch (rounds 4/5: compiler
// re-serialized any pressure it was allowed to).
#define WGBAR() do { \
    asm volatile("s_waitcnt lgkmcnt(0)" ::: "memory"); \
    __builtin_amdgcn_s_barrier(); \
  } while (0)

struct Row24 { float4 a, b, c, d, e, f; };   // 24 contiguous floats (8 RGB px)

__device__ __forceinline__ Row24 loadrow(const float* __restrict__ p) {
  const float4* q = (const float4*)p;
  Row24 r;
  r.a = q[0]; r.b = q[1]; r.c = q[2]; r.d = q[3]; r.e = q[4]; r.f = q[5];
  return r;
}

// Color-convert one row of 8 pixels: yields level-shifted luma yv[8] and the
// 2x2-downsampled chroma contribution (4 values, combined with row l^1 via
// shfl_xor(1); sum is commutative so all lanes hold identical values).
__device__ __forceinline__ void convert_row(const Row24& R, float yv[8],
                                            float cbds[4], float crds[4]) {
  float px[24] = {R.a.x,R.a.y,R.a.z,R.a.w, R.b.x,R.b.y,R.b.z,R.b.w,
                  R.c.x,R.c.y,R.c.z,R.c.w, R.d.x,R.d.y,R.d.z,R.d.w,
                  R.e.x,R.e.y,R.e.z,R.e.w, R.f.x,R.f.y,R.f.z,R.f.w};
  float cbv[8], crv[8];
  #pragma unroll
  for (int p = 0; p < 8; ++p) {
    float rc = fminf(fmaxf(floorf(exact_div(px[3*p+0], C255, RC255)), 0.0f), 255.0f);
    float gc = fminf(fmaxf(floorf(exact_div(px[3*p+1], C255, RC255)), 0.0f), 255.0f);
    float bc = fminf(fmaxf(floorf(exact_div(px[3*p+2], C255, RC255)), 0.0f), 255.0f);
    float y  =  0.299f*rc + 0.587f*gc + 0.114f*bc;
    float cb = -0.168736f*rc - 0.331264f*gc + 0.5f*bc + 128.0f;
    float cr =  0.5f*rc - 0.418688f*gc - 0.081312f*bc + 128.0f;
    yv[p]  = y - 128.0f;
    cbv[p] = cb;
    crv[p] = cr;
  }
  #pragma unroll
  for (int k = 0; k < 4; ++k) {
    float hcb = cbv[2*k] + cbv[2*k+1];      // reference order: (c00+c01)+(c10+c11)
    float hcr = crv[2*k] + crv[2*k+1];
    float ocb = __shfl_xor(hcb, 1, 64);
    float ocr = __shfl_xor(hcr, 1, 64);
    cbds[k] = (hcb + ocb)*0.25f - 128.0f;
    crds[k] = (hcr + ocr)*0.25f - 128.0f;
  }
}

// Fused 3-pipeline DCT->quant->IDCT for one 16x64 tile (2 luma blocks in regs
// + 1 chroma block via LDS). vA/vB hold luma rows l and l+8 in/out.
__device__ __forceinline__ void phaseB(float vA[8], float vB[8], int g, int l,
                                       float* CbT, float* CrT,
                                       const float* QTl, const float* RQl,
                                       const float* QTc, const float* RQc) {
  float* rowp = ((g & 4) ? CrT : CbT) + l*36 + (g & 3)*8;
  float4 L0 = *(const float4*)&rowp[0];
  float4 L1 = *(const float4*)&rowp[4];
  float vC[8] = {L0.x,L0.y,L0.z,L0.w,L1.x,L1.y,L1.z,L1.w};
  float uA[8], uB[8], uC[8];
  dct8(vA, uA); dct8(vB, uB); dct8(vC, uC);   // row DCTs
  xpose3(uA, uB, uC, l);
  dct8(uA, vA); quant8(vA, QTl, RQl);         // col DCT + quant
  dct8(uB, vB); quant8(vB, QTl, RQl);
  dct8(uC, vC); quant8(vC, QTc, RQc);         // chroma table (round-3 lesson)
  idct8(vA, uA); idct8(vB, uB); idct8(vC, uC);
  xpose3(uA, uB, uC, l);
  idct8(uA, vA); idct8(uB, vB); idct8(uC, vC);
  *(float4*)&rowp[0] = make_float4(vC[0],vC[1],vC[2],vC[3]);
  *(float4*)&rowp[4] = make_float4(vC[4],vC[5],vC[6],vC[7]);
}

__device__ __forceinline__ void outputTile(const float vA[8], const float vB[8],
                                           int g, int l,
                                           const float* CbT, const float* CrT,
                                           float* __restrict__ out,
                                           size_t imgbase, int row0, int col0) {
  #pragma unroll
  for (int rr = 0; rr < 2; ++rr) {
    const int r = l + rr*8;
    const int crow = r >> 1;
    float4 CbF = *(const float4*)&CbT[crow*36 + g*4];
    float4 CrF = *(const float4*)&CrT[crow*36 + g*4];
    float cbq[4] = {CbF.x,CbF.y,CbF.z,CbF.w};
    float crq[4] = {CrF.x,CrF.y,CrF.z,CrF.w};
    float ov[24];
    #pragma unroll
    for (int p = 0; p < 8; ++p) {
      float y2  = (rr ? vB[p] : vA[p]) + 128.0f;
      float cb2 = cbq[p>>1] + 128.0f;
      float cr2 = crq[p>>1] + 128.0f;
      float r2 = y2 + 1.402f*(cr2 - 128.0f);
      float g2 = y2 - 0.344136f*(cb2 - 128.0f) - 0.714136f*(cr2 - 128.0f);
      float b2 = y2 + 1.772f*(cb2 - 128.0f);
      ov[3*p+0] = exact_div(rintf(fminf(fmaxf(r2, 0.0f), 255.0f)), 255.0f, C255);
      ov[3*p+1] = exact_div(rintf(fminf(fmaxf(g2, 0.0f), 255.0f)), 255.0f, C255);
      ov[3*p+2] = exact_div(rintf(fminf(fmaxf(b2, 0.0f), 255.0f)), 255.0f, C255);
    }
    float* op = out + (imgbase + (size_t)(row0 + r)*512 + col0)*3;
    ((float4*)op)[0] = make_float4(ov[0], ov[1], ov[2], ov[3]);
    ((float4*)op)[1] = make_float4(ov[4], ov[5], ov[6], ov[7]);
    ((float4*)op)[2] = make_float4(ov[8], ov[9], ov[10],ov[11]);
    ((float4*)op)[3] = make_float4(ov[12],ov[13],ov[14],ov[15]);
    ((float4*)op)[4] = make_float4(ov[16],ov[17],ov[18],ov[19]);
    ((float4*)op)[5] = make_float4(ov[20],ov[21],ov[22],ov[23]);
  }
}

// 128 threads = 2 waves; each wave independently processes TWO 16x64 tiles
// (rows w*32+0..15 and +16..31 of the WG's 64-row stripe) with register
// prefetch: tile1's global loads are issued before tile0's compute phases so
// HBM latency/BW streams under VALU+DS work. Grid (8,8,32) = 2048 WGs.
__global__ __launch_bounds__(128, 4) void jpeg_rt(const float* __restrict__ in,
                                                  float* __restrict__ out)
{
  __shared__ __align__(16) float Cbp[2][2][8][36];  // [wave][tile] chroma planes
  __shared__ __align__(16) float Crp[2][2][8][36];
  __shared__ __align__(16) float QTs[2][8][8];      // [plane][col l][row m]
  __shared__ __align__(16) float RQs[2][8][8];      // correctly-rounded 1/Q

  const int t    = threadIdx.x;   // 0..127
  const int w    = t >> 6;        // wave 0..1
  const int lane = t & 63;
  const int g    = lane >> 3;     // group 0..7 = luma block-col
  const int l    = lane & 7;      // row within 8x8 block
  const int tx   = blockIdx.x;    // 0..7
  const int ty   = blockIdx.y;    // 0..7
  const int img  = blockIdx.z;    // 0..31

  // Quant tables (transposed) + exact reciprocals: 128 threads cover 2x8x8.
  {
    const int pl = t >> 6, i = (t >> 3) & 7, m = t & 7;
    const float q = pl ? QCt[m][i] : QLt[m][i];
    QTs[pl][i][m] = q;
    RQs[pl][i][m] = 1.0f / q;
  }

  const size_t imgbase = (size_t)img * (512*512);
  const int col0 = tx*64 + g*8;
  const int row0 = ty*64 + w*32;        // tile0: rows row0..+15, tile1: +16..+31

  const float* QTl = &QTs[0][l][0];
  const float* RQl = &RQs[0][l][0];
  const float* QTc = &QTs[1][l][0];
  const float* RQc = &RQs[1][l][0];
  float* Cb0 = &Cbp[w][0][0][0];  float* Cr0 = &Crp[w][0][0][0];
  float* Cb1 = &Cbp[w][1][0][0];  float* Cr1 = &Crp[w][1][0][0];

  // ---- tile0 loads + convert
  Row24 R00 = loadrow(in + (imgbase + (size_t)(row0 + l    )*512 + col0)*3);
  Row24 R01 = loadrow(in + (imgbase + (size_t)(row0 + l + 8)*512 + col0)*3);
  float vA0[8], vB0[8];
  {
    float cb0[4], cr0[4], cb1[4], cr1[4];
    convert_row(R00, vA0, cb0, cr0);
    convert_row(R01, vB0, cb1, cr1);
    if ((l & 1) == 0) {
      const int c0 = (l >> 1)*36 + g*4;       // crow rr=0
      const int c1 = ((l >> 1) + 4)*36 + g*4; // crow rr=1
      *(float4*)&Cb0[c0] = make_float4(cb0[0],cb0[1],cb0[2],cb0[3]);
      *(float4*)&Cr0[c0] = make_float4(cr0[0],cr0[1],cr0[2],cr0[3]);
      *(float4*)&Cb0[c1] = make_float4(cb1[0],cb1[1],cb1[2],cb1[3]);
      *(float4*)&Cr0[c1] = make_float4(cr1[0],cr1[1],cr1[2],cr1[3]);
    }
  }
  // ---- prefetch tile1 row set 0 (in flight across phaseB(t0))
  Row24 R10 = loadrow(in + (imgbase + (size_t)(row0 + 16 + l)*512 + col0)*3);

  WGBAR();   // (1) tables + tile0 chroma visible; prefetch stays in flight

  phaseB(vA0, vB0, g, l, Cb0, Cr0, QTl, RQl, QTc, RQc);

  // ---- prefetch tile1 row set 1 (in flight across output(t0)+convert(R10))
  Row24 R11 = loadrow(in + (imgbase + (size_t)(row0 + 24 + l)*512 + col0)*3);

  WGBAR();   // (2) tile0 chroma rec visible

  outputTile(vA0, vB0, g, l, Cb0, Cr0, out, imgbase, row0, col0);

  // ---- tile1 convert (prefetched data)
  float vA1[8], vB1[8];
  {
    float cb0[4], cr0[4], cb1[4], cr1[4];
    convert_row(R10, vA1, cb0, cr0);
    convert_row(R11, vB1, cb1, cr1);
    if ((l & 1) == 0) {
      const int c0 = (l >> 1)*36 + g*4;
      const int c1 = ((l >> 1) + 4)*36 + g*4;
      *(float4*)&Cb1[c0] = make_float4(cb0[0],cb0[1],cb0[2],cb0[3]);
      *(float4*)&Cr1[c0] = make_float4(cr0[0],cr0[1],cr0[2],cr0[3]);
      *(float4*)&Cb1[c1] = make_float4(cb1[0],cb1[1],cb1[2],cb1[3]);
      *(float4*)&Cr1[c1] = make_float4(cr1[0],cr1[1],cr1[2],cr1[3]);
    }
  }
  WGBAR();   // (3) tile1 chroma visible

  phaseB(vA1, vB1, g, l, Cb1, Cr1, QTl, RQl, QTc, RQc);

  WGBAR();   // (4) tile1 chroma rec visible

  outputTile(vA1, vB1, g, l, Cb1, Cr1, out, imgbase, row0 + 16, col0);
}

extern "C" void kernel_launch(void* const* d_in, const int* in_sizes, int n_in,
                              void* d_out, int out_size, void* d_ws, size_t ws_size,
                              hipStream_t stream) {
  (void)in_sizes; (void)n_in; (void)d_ws; (void)ws_size; (void)out_size;
  const float* x = (const float*)d_in[0];
  float* out = (float*)d_out;
  dim3 grid(8, 8, 32);   // W/64, H/64, B
  jpeg_rt<<<grid, dim3(128), 0, stream>>>(x, out);
}

// Round 8
// 183.237 us; speedup vs baseline: 1.0663x; 1.0663x over previous
//
#include <hip/hip_runtime.h>
#include <cstddef>

// DCT-II matrix (float32 cast of numpy's float64 values)
static constexpr float D8[8][8] = {
  { 0.35355339059327373f, 0.35355339059327373f, 0.35355339059327373f, 0.35355339059327373f,
    0.35355339059327373f, 0.35355339059327373f, 0.35355339059327373f, 0.35355339059327373f},
  { 0.4903926402016152f,  0.4157348061512726f,  0.27778511650980114f, 0.09754516100806417f,
   -0.09754516100806417f,-0.27778511650980114f,-0.4157348061512726f, -0.4903926402016152f},
  { 0.46193976625564337f, 0.19134171618254492f,-0.19134171618254492f,-0.46193976625564337f,
   -0.46193976625564337f,-0.19134171618254492f, 0.19134171618254492f, 0.46193976625564337f},
  { 0.4157348061512726f, -0.09754516100806417f,-0.4903926402016152f, -0.27778511650980114f,
    0.27778511650980114f, 0.4903926402016152f,  0.09754516100806417f,-0.4157348061512726f},
  { 0.35355339059327373f,-0.35355339059327373f,-0.35355339059327373f, 0.35355339059327373f,
    0.35355339059327373f,-0.35355339059327373f,-0.35355339059327373f, 0.35355339059327373f},
  { 0.27778511650980114f,-0.4903926402016152f,  0.09754516100806417f, 0.4157348061512726f,
   -0.4157348061512726f, -0.09754516100806417f, 0.4903926402016152f, -0.27778511650980114f},
  { 0.19134171618254492f,-0.46193976625564337f, 0.46193976625564337f,-0.19134171618254492f,
   -0.19134171618254492f, 0.46193976625564337f,-0.46193976625564337f, 0.19134171618254492f},
  { 0.09754516100806417f,-0.27778511650980114f, 0.4157348061512726f, -0.4903926402016152f,
    0.4903926402016152f, -0.4157348061512726f,  0.27778511650980114f,-0.09754516100806417f},
};

// Quality-95 quant tables: q = clamp(floor((base*10+50)/100), 1, 255)
static constexpr float QLt[8][8] = {
  {2,1,1,2,2,4,5,6},
  {1,1,1,2,3,6,6,6},
  {1,1,2,2,4,6,7,6},
  {1,2,2,3,5,9,8,6},
  {2,2,4,6,7,11,10,8},
  {2,4,6,6,8,10,11,9},
  {5,6,8,9,10,12,12,10},
  {7,9,10,10,11,10,10,10},
};
static constexpr float QCt[8][8] = {
  {2,2,2,5,10,10,10,10},
  {2,2,3,7,10,10,10,10},
  {2,3,6,10,10,10,10,10},
  {5,7,10,10,10,10,10,10},
  {10,10,10,10,10,10,10,10},
  {10,10,10,10,10,10,10,10},
  {10,10,10,10,10,10,10,10},
  {10,10,10,10,10,10,10,10},
};

static constexpr float C255  = (float)(1.0/255.0);  // fl(1/255): matches jnp's f32 divisor
static constexpr float RC255 = 1.0f / C255;         // correctly-rounded reciprocal (constexpr IEEE)

// Markstein exactly-rounded division by constant c with precomputed r = fl(1/c):
// bit-identical to IEEE x/c, 3 VALU ops. Used where a floor/rint decision
// depends on the quotient.
__device__ __forceinline__ float exact_div(float x, float c, float r) {
  float q0 = x * r;
  float e  = fmaf(-c, q0, x);
  return fmaf(e, r, q0);
}

// u[k] = sum_j D8[k][j] * x[j]
__device__ __forceinline__ void dct8(const float x[8], float u[8]) {
  #pragma unroll
  for (int k = 0; k < 8; ++k) {
    float a = D8[k][0] * x[0];
    #pragma unroll
    for (int j = 1; j < 8; ++j) a += D8[k][j] * x[j];
    u[k] = a;
  }
}

// u[j] = sum_m x[m] * D8[m][j]
__device__ __forceinline__ void idct8(const float x[8], float u[8]) {
  #pragma unroll
  for (int j = 0; j < 8; ++j) {
    float a = x[0] * D8[0][j];
    #pragma unroll
    for (int m = 1; m < 8; ++m) a += x[m] * D8[m][j];
    u[j] = a;
  }
}

// 8x8 transpose via group-local LDS scratch (one 8-lane group per block).
// Replaces the shfl_xor butterfly: 10 DS ops, zero VALU, ONE latency hop
// (vs 24 bpermute + ~36 cndmask + 3 dependent stages). Same-wave lockstep;
// DS ops execute in order within a wave, so no barrier. S points to this
// group's [8][12] scratch (row stride 48B keeps b128 reads aligned).
__device__ __forceinline__ void xpose_lds(float v[8], int l, float* S) {
  #pragma unroll
  for (int m = 0; m < 8; ++m) S[m*12 + l] = v[m];   // write my column
  asm volatile("" ::: "memory");                    // pin write<read order
  float4 a = *(const float4*)&S[l*12 + 0];          // read my row
  float4 b = *(const float4*)&S[l*12 + 4];
  asm volatile("" ::: "memory");
  v[0]=a.x; v[1]=a.y; v[2]=a.z; v[3]=a.w;
  v[4]=b.x; v[5]=b.y; v[6]=b.z; v[7]=b.w;
}

__device__ __forceinline__ void quant8(float v[8], const float* QT, const float* RQ) {
  float4 Q0 = *(const float4*)&QT[0];
  float4 Q1 = *(const float4*)&QT[4];
  float4 R0 = *(const float4*)&RQ[0];
  float4 R1 = *(const float4*)&RQ[4];
  float qv[8] = {Q0.x,Q0.y,Q0.z,Q0.w,Q1.x,Q1.y,Q1.z,Q1.w};
  float rv[8] = {R0.x,R0.y,R0.z,R0.w,R1.x,R1.y,R1.z,R1.w};
  #pragma unroll
  for (int m = 0; m < 8; ++m)
    v[m] = rintf(exact_div(v[m], qv[m], rv[m])) * qv[m];
}

// Full per-block pipeline; v holds spatial row `l` in/out.
__device__ __forceinline__ void jblk8(float v[8], int l, float* S,
                                      const float* QT, const float* RQ) {
  float u[8];
  dct8(v, u);
  xpose_lds(u, l, S);
  dct8(u, v);
  quant8(v, QT, RQ);
  idct8(v, u);
  xpose_lds(u, l, S);
  idct8(u, v);
}

struct Row24 { float4 a, b, c, d, e, f; };   // 24 contiguous floats (8 RGB px)

__device__ __forceinline__ Row24 loadrow(const float* __restrict__ p) {
  const float4* q = (const float4*)p;
  Row24 r;
  r.a = q[0]; r.b = q[1]; r.c = q[2]; r.d = q[3]; r.e = q[4]; r.f = q[5];
  return r;
}

// Color-convert one row of 8 pixels -> level-shifted luma yv[8] + the 2x2
// downsampled chroma (4 values; vertical pair via shfl_xor(1): lanes l, l^1
// hold adjacent image rows). Input clamp dropped: x in [0,1) => floor of
// x/fl(1/255) is already in [0,255] (max 255.000015 -> 255).
__device__ __forceinline__ void convert_row(const Row24& R, float yv[8],
                                            float cbds[4], float crds[4]) {
  float px[24] = {R.a.x,R.a.y,R.a.z,R.a.w, R.b.x,R.b.y,R.b.z,R.b.w,
                  R.c.x,R.c.y,R.c.z,R.c.w, R.d.x,R.d.y,R.d.z,R.d.w,
                  R.e.x,R.e.y,R.e.z,R.e.w, R.f.x,R.f.y,R.f.z,R.f.w};
  float cbv[8], crv[8];
  #pragma unroll
  for (int p = 0; p < 8; ++p) {
    float rc = floorf(exact_div(px[3*p+0], C255, RC255));
    float gc = floorf(exact_div(px[3*p+1], C255, RC255));
    float bc = floorf(exact_div(px[3*p+2], C255, RC255));
    float y  =  0.299f*rc + 0.587f*gc + 0.114f*bc;
    float cb = -0.168736f*rc - 0.331264f*gc + 0.5f*bc + 128.0f;
    float cr =  0.5f*rc - 0.418688f*gc - 0.081312f*bc + 128.0f;
    yv[p]  = y - 128.0f;
    cbv[p] = cb;
    crv[p] = cr;
  }
  #pragma unroll
  for (int k = 0; k < 4; ++k) {
    float hcb = cbv[2*k] + cbv[2*k+1];      // reference order: (c00+c01)+(c10+c11)
    float hcr = crv[2*k] + crv[2*k+1];
    float ocb = __shfl_xor(hcb, 1, 64);
    float ocr = __shfl_xor(hcr, 1, 64);
    cbds[k] = (hcb + ocb)*0.25f - 128.0f;
    crds[k] = (hcr + ocr)*0.25f - 128.0f;
  }
}

// Tile: 16 rows x 128 cols. Grid (4, 32, 32) = 4096 WGs x 256 threads (round
// 2's winning launch shape). 32 groups of 8 lanes; each group owns one luma
// 8x8 block (rows loaded directly in DCT layout -> luma never touches LDS);
// 16 chroma blocks on t<128. Transposes via group-local LDS scratch.
__global__ __launch_bounds__(256) void jpeg_rt(const float* __restrict__ in,
                                               float* __restrict__ out)
{
  __shared__ __align__(16) float Scr[32][100];  // per-group [8][12] + 4 pad
  __shared__ __align__(16) float Cbp[8][68];    // half-res chroma planes
  __shared__ __align__(16) float Crp[8][68];    // (stride 68: ~2-way aliasing)
  __shared__ __align__(16) float QTs[2][8][8];  // [plane][col l][row m] = Q[m][l]
  __shared__ __align__(16) float RQs[2][8][8];  // correctly-rounded 1/Q

  const int t   = threadIdx.x;  // 0..255
  const int g   = t >> 3;       // group 0..31
  const int l   = t & 7;        // row within 8x8 block
  const int br  = g >> 4;       // luma block-row (0..1)
  const int bc  = g & 15;       // luma block-col (0..15)
  const int tx  = blockIdx.x;   // 0..3
  const int ty  = blockIdx.y;   // 0..31
  const int img = blockIdx.z;   // 0..31

  // Quant tables (transposed) + exact reciprocals.
  if (t < 128) {
    const int pl = t >> 6, i = (t >> 3) & 7, m = t & 7;
    const float q = pl ? QCt[m][i] : QLt[m][i];
    QTs[pl][i][m] = q;
    RQs[pl][i][m] = 1.0f / q;
  }

  const size_t imgbase = (size_t)img * (512*512);
  const int row  = ty*16 + br*8 + l;   // this thread's image row
  const int col0 = tx*128 + bc*8;

  // ---------------- stage 1: load one 8-px row, convert, emit chroma to LDS
  float vY[8];
  {
    Row24 R = loadrow(in + (imgbase + (size_t)row*512 + col0)*3);
    float cbds[4], crds[4];
    convert_row(R, vY, cbds, crds);
    if ((l & 1) == 0) {                      // even lane = top row of the pair
      const int crow = br*4 + (l >> 1);      // tile chroma row 0..7
      *(float4*)&Cbp[crow][bc*4] = make_float4(cbds[0],cbds[1],cbds[2],cbds[3]);
      *(float4*)&Crp[crow][bc*4] = make_float4(crds[0],crds[1],crds[2],crds[3]);
    }
  }
  __syncthreads();   // tables + chroma planes visible

  // ---------------- luma pipeline (regs + group scratch only)
  jblk8(vY, l, &Scr[g][0], &QTs[0][l][0], &RQs[0][l][0]);

  // ---------------- chroma: 16 blocks on t<128 (groups 0..15 = waves 0..1,
  // reusing their own groups' scratch — in-order within wave, no barrier)
  if (t < 128) {
    const int pl = g >> 3;                  // 0 = Cb, 1 = Cr
    float* plane = pl ? &Crp[0][0] : &Cbp[0][0];
    float* rowp  = plane + l*68 + (g & 7)*8;
    float4 L0 = *(const float4*)&rowp[0];
    float4 L1 = *(const float4*)&rowp[4];
    float vC[8] = {L0.x,L0.y,L0.z,L0.w,L1.x,L1.y,L1.z,L1.w};
    jblk8(vC, l, &Scr[g][0], &QTs[1][l][0], &RQs[1][l][0]);  // chroma table!
    *(float4*)&rowp[0] = make_float4(vC[0],vC[1],vC[2],vC[3]);
    *(float4*)&rowp[4] = make_float4(vC[4],vC[5],vC[6],vC[7]);
  }
  __syncthreads();   // chroma rec visible

  // ---------------- output: luma rec in regs; upsample chroma from LDS.
  // /255 after rintf carries no rounding decision -> plain multiply by
  // fl(1/255) (<=1 ulp vs exact division; threshold slack 0.0069).
  {
    const int crow = br*4 + (l >> 1);
    float4 CbF = *(const float4*)&Cbp[crow][bc*4];
    float4 CrF = *(const float4*)&Crp[crow][bc*4];
    float cbq[4] = {CbF.x,CbF.y,CbF.z,CbF.w};
    float crq[4] = {CrF.x,CrF.y,CrF.z,CrF.w};
    float ov[24];
    #pragma unroll
    for (int p = 0; p < 8; ++p) {
      float y2  = vY[p] + 128.0f;
      float cb2 = cbq[p>>1] + 128.0f;
      float cr2 = crq[p>>1] + 128.0f;
      float r2 = y2 + 1.402f*(cr2 - 128.0f);
      float g2 = y2 - 0.344136f*(cb2 - 128.0f) - 0.714136f*(cr2 - 128.0f);
      float b2 = y2 + 1.772f*(cb2 - 128.0f);
      ov[3*p+0] = rintf(fminf(fmaxf(r2, 0.0f), 255.0f)) * C255;
      ov[3*p+1] = rintf(fminf(fmaxf(g2, 0.0f), 255.0f)) * C255;
      ov[3*p+2] = rintf(fminf(fmaxf(b2, 0.0f), 255.0f)) * C255;
    }
    float* op = out + (imgbase + (size_t)row*512 + col0)*3;
    ((float4*)op)[0] = make_float4(ov[0], ov[1], ov[2], ov[3]);
    ((float4*)op)[1] = make_float4(ov[4], ov[5], ov[6], ov[7]);
    ((float4*)op)[2] = make_float4(ov[8], ov[9], ov[10],ov[11]);
    ((float4*)op)[3] = make_float4(ov[12],ov[13],ov[14],ov[15]);
    ((float4*)op)[4] = make_float4(ov[16],ov[17],ov[18],ov[19]);
    ((float4*)op)[5] = make_float4(ov[20],ov[21],ov[22],ov[23]);
  }
}

extern "C" void kernel_launch(void* const* d_in, const int* in_sizes, int n_in,
                              void* d_out, int out_size, void* d_ws, size_t ws_size,
                              hipStream_t stream) {
  (void)in_sizes; (void)n_in; (void)d_ws; (void)ws_size; (void)out_size;
  const float* x = (const float*)d_in[0];
  float* out = (float*)d_out;
  dim3 grid(4, 32, 32);   // W/128, H/16, B
  jpeg_rt<<<grid, dim3(256), 0, stream>>>(x, out);
}

// Round 9
// 179.690 us; speedup vs baseline: 1.0874x; 1.0197x over previous
//
#include <hip/hip_runtime.h>
#include <cstddef>

// DCT-II matrix (float32 cast of numpy's float64 values)
static constexpr float D8[8][8] = {
  { 0.35355339059327373f, 0.35355339059327373f, 0.35355339059327373f, 0.35355339059327373f,
    0.35355339059327373f, 0.35355339059327373f, 0.35355339059327373f, 0.35355339059327373f},
  { 0.4903926402016152f,  0.4157348061512726f,  0.27778511650980114f, 0.09754516100806417f,
   -0.09754516100806417f,-0.27778511650980114f,-0.4157348061512726f, -0.4903926402016152f},
  { 0.46193976625564337f, 0.19134171618254492f,-0.19134171618254492f,-0.46193976625564337f,
   -0.46193976625564337f,-0.19134171618254492f, 0.19134171618254492f, 0.46193976625564337f},
  { 0.4157348061512726f, -0.09754516100806417f,-0.4903926402016152f, -0.27778511650980114f,
    0.27778511650980114f, 0.4903926402016152f,  0.09754516100806417f,-0.4157348061512726f},
  { 0.35355339059327373f,-0.35355339059327373f,-0.35355339059327373f, 0.35355339059327373f,
    0.35355339059327373f,-0.35355339059327373f,-0.35355339059327373f, 0.35355339059327373f},
  { 0.27778511650980114f,-0.4903926402016152f,  0.09754516100806417f, 0.4157348061512726f,
   -0.4157348061512726f, -0.09754516100806417f, 0.4903926402016152f, -0.27778511650980114f},
  { 0.19134171618254492f,-0.46193976625564337f, 0.46193976625564337f,-0.19134171618254492f,
   -0.19134171618254492f, 0.46193976625564337f,-0.46193976625564337f, 0.19134171618254492f},
  { 0.09754516100806417f,-0.27778511650980114f, 0.4157348061512726f, -0.4903926402016152f,
    0.4903926402016152f, -0.4157348061512726f,  0.27778511650980114f,-0.09754516100806417f},
};

// Quality-95 quant tables: q = clamp(floor((base*10+50)/100), 1, 255)
static constexpr float QLt[8][8] = {
  {2,1,1,2,2,4,5,6},
  {1,1,1,2,3,6,6,6},
  {1,1,2,2,4,6,7,6},
  {1,2,2,3,5,9,8,6},
  {2,2,4,6,7,11,10,8},
  {2,4,6,6,8,10,11,9},
  {5,6,8,9,10,12,12,10},
  {7,9,10,10,11,10,10,10},
};
static constexpr float QCt[8][8] = {
  {2,2,2,5,10,10,10,10},
  {2,2,3,7,10,10,10,10},
  {2,3,6,10,10,10,10,10},
  {5,7,10,10,10,10,10,10},
  {10,10,10,10,10,10,10,10},
  {10,10,10,10,10,10,10,10},
  {10,10,10,10,10,10,10,10},
  {10,10,10,10,10,10,10,10},
};

static constexpr float C255  = (float)(1.0/255.0);  // fl(1/255): matches jnp's f32 divisor
static constexpr float RC255 = 1.0f / C255;         // correctly-rounded reciprocal (constexpr IEEE)

// Markstein exactly-rounded division by constant c with precomputed r = fl(1/c):
// bit-identical to IEEE x/c, 3 VALU ops. Used where a floor/rint decision
// depends on the quotient.
__device__ __forceinline__ float exact_div(float x, float c, float r) {
  float q0 = x * r;
  float e  = fmaf(-c, q0, x);
  return fmaf(e, r, q0);
}

// u[k] = sum_j D8[k][j] * x[j]
__device__ __forceinline__ void dct8(const float x[8], float u[8]) {
  #pragma unroll
  for (int k = 0; k < 8; ++k) {
    float a = D8[k][0] * x[0];
    #pragma unroll
    for (int j = 1; j < 8; ++j) a += D8[k][j] * x[j];
    u[k] = a;
  }
}

// u[j] = sum_m x[m] * D8[m][j]
__device__ __forceinline__ void idct8(const float x[8], float u[8]) {
  #pragma unroll
  for (int j = 0; j < 8; ++j) {
    float a = x[0] * D8[0][j];
    #pragma unroll
    for (int m = 1; m < 8; ++m) a += x[m] * D8[m][j];
    u[j] = a;
  }
}

// 8x8 transpose via group-local LDS scratch, bank-engineered:
//   row stride 13 floats (ODD), group stride 104 floats (104%32 = 8).
//   write m: bank = (8g + 13m + l) %32  -> fixed m: 8g+l = exactly 2-way (free)
//   read  m: bank = (8g + 13l + m) %32  -> 13 invertible mod 32; collisions
//            only at (dl=0, dg=4) = exactly 2-way (free).
// Round-8 version (stride 12/100, b128 reads) was ~8-way on reads: both
// strides even => only 8 reachable start banks (1.97M conflicts measured).
// All-scalar DS ops, zero VALU, same-wave lockstep (no barrier needed).
__device__ __forceinline__ void xpose_scr(float v[8], int l, float* S) {
  #pragma unroll
  for (int m = 0; m < 8; ++m) S[m*13 + l] = v[m];   // write my column
  asm volatile("" ::: "memory");                    // pin write<read order
  float u[8];
  #pragma unroll
  for (int m = 0; m < 8; ++m) u[m] = S[l*13 + m];   // read my row
  asm volatile("" ::: "memory");
  #pragma unroll
  for (int m = 0; m < 8; ++m) v[m] = u[m];
}

__device__ __forceinline__ void quant8(float v[8], const float* QT, const float* RQ) {
  float4 Q0 = *(const float4*)&QT[0];
  float4 Q1 = *(const float4*)&QT[4];
  float4 R0 = *(const float4*)&RQ[0];
  float4 R1 = *(const float4*)&RQ[4];
  float qv[8] = {Q0.x,Q0.y,Q0.z,Q0.w,Q1.x,Q1.y,Q1.z,Q1.w};
  float rv[8] = {R0.x,R0.y,R0.z,R0.w,R1.x,R1.y,R1.z,R1.w};
  #pragma unroll
  for (int m = 0; m < 8; ++m)
    v[m] = rintf(exact_div(v[m], qv[m], rv[m])) * qv[m];
}

// Full per-block pipeline; v holds spatial row `l` in/out.
__device__ __forceinline__ void jblk8(float v[8], int l, float* S,
                                      const float* QT, const float* RQ) {
  float u[8];
  dct8(v, u);
  xpose_scr(u, l, S);
  dct8(u, v);
  quant8(v, QT, RQ);
  idct8(v, u);
  xpose_scr(u, l, S);
  idct8(u, v);
}

// Tile: 16 rows x 128 cols. Grid (4, 32, 32) = 4096 WGs x 256 threads —
// round 2's proven skeleton (coalesced 2-row x 4-px global I/O via Yp
// staging, 2 barriers, chroma after luma) + round 8's proven arithmetic
// cuts + the bank-engineered scratch transpose.
__global__ __launch_bounds__(256) void jpeg_rt(const float* __restrict__ in,
                                               float* __restrict__ out)
{
  __shared__ __align__(16) float Yp[16][132];   // luma plane (stride 132)
  __shared__ __align__(16) float Scr[32][104];  // per-group transpose scratch
  __shared__ __align__(16) float Cbp[8][68];    // half-res chroma planes
  __shared__ __align__(16) float Crp[8][68];
  __shared__ __align__(16) float QTs[2][8][8];  // [plane][col l][row m] = Q[m][l]
  __shared__ __align__(16) float RQs[2][8][8];  // correctly-rounded 1/Q

  const int t   = threadIdx.x;
  const int tx  = blockIdx.x;   // 0..3
  const int ty  = blockIdx.y;   // 0..31
  const int img = blockIdx.z;   // 0..31

  const int pr = t >> 5;        // patch row 0..7   (pixel rows 2pr, 2pr+1)
  const int pc = t & 31;        // patch col 0..31  (pixel cols 4pc..4pc+3)

  // Quant tables (transposed) + exact reciprocals.
  if (t < 128) {
    const int pl = t >> 6, i = (t >> 3) & 7, m = t & 7;
    const float q = pl ? QCt[m][i] : QLt[m][i];
    QTs[pl][i][m] = q;
    RQs[pl][i][m] = 1.0f / q;
  }

  // ---------------- stage 1: load 2x4 patch, color convert, plane writes.
  // Input clamp dropped (R8-proven): x in [0,1) => floor(x/fl(1/255)) is
  // already in [0,255].
  {
    float yv[2][4];
    float cbv[2][4], crv[2][4];
    #pragma unroll
    for (int rr = 0; rr < 2; ++rr) {
      const size_t grow = (size_t)img * 512 + (size_t)(ty*16 + 2*pr + rr);
      const float* rp = in + (grow*512 + (size_t)(tx*128 + 4*pc))*3;
      float4 A = ((const float4*)rp)[0];
      float4 Bq = ((const float4*)rp)[1];
      float4 Cq = ((const float4*)rp)[2];
      float px[12] = {A.x,A.y,A.z,A.w,Bq.x,Bq.y,Bq.z,Bq.w,Cq.x,Cq.y,Cq.z,Cq.w};
      #pragma unroll
      for (int p = 0; p < 4; ++p) {
        float r = floorf(exact_div(px[3*p+0], C255, RC255));
        float g = floorf(exact_div(px[3*p+1], C255, RC255));
        float b = floorf(exact_div(px[3*p+2], C255, RC255));
        float y  =  0.299f*r + 0.587f*g + 0.114f*b;
        float cb = -0.168736f*r - 0.331264f*g + 0.5f*b + 128.0f;
        float cr =  0.5f*r - 0.418688f*g - 0.081312f*b + 128.0f;
        yv[rr][p]  = y - 128.0f;
        cbv[rr][p] = cb;
        crv[rr][p] = cr;
      }
    }
    *(float4*)&Yp[2*pr+0][4*pc] = make_float4(yv[0][0],yv[0][1],yv[0][2],yv[0][3]);
    *(float4*)&Yp[2*pr+1][4*pc] = make_float4(yv[1][0],yv[1][1],yv[1][2],yv[1][3]);
    float cb0 = ((cbv[0][0]+cbv[0][1]) + (cbv[1][0]+cbv[1][1]))*0.25f - 128.0f;
    float cb1 = ((cbv[0][2]+cbv[0][3]) + (cbv[1][2]+cbv[1][3]))*0.25f - 128.0f;
    float cr0 = ((crv[0][0]+crv[0][1]) + (crv[1][0]+crv[1][1]))*0.25f - 128.0f;
    float cr1 = ((crv[0][2]+crv[0][3]) + (crv[1][2]+crv[1][3]))*0.25f - 128.0f;
    *(float2*)&Cbp[pr][2*pc] = make_float2(cb0, cb1);
    *(float2*)&Crp[pr][2*pc] = make_float2(cr0, cr1);
  }
  __syncthreads();

  // ---------------- luma: full DCT -> quant -> IDCT per 8x8 block.
  // Group b = 8 consecutive lanes owns one block; lane l holds row l.
  {
    const int b = t >> 3, l = t & 7;
    const int br = b >> 4, bc = b & 15;
    float* rowp = &Yp[br*8 + l][bc*8];
    float4 L0 = *(const float4*)&rowp[0];
    float4 L1 = *(const float4*)&rowp[4];
    float v[8] = {L0.x, L0.y, L0.z, L0.w, L1.x, L1.y, L1.z, L1.w};
    jblk8(v, l, &Scr[b][0], &QTs[0][l][0], &RQs[0][l][0]);
    *(float4*)&rowp[0] = make_float4(v[0],v[1],v[2],v[3]);
    *(float4*)&rowp[4] = make_float4(v[4],v[5],v[6],v[7]);
  }
  // ---------------- chroma: 16 blocks on t<128 (groups 0..15 belong to
  // waves 0-1 in both phases — same-wave scratch reuse, no barrier)
  if (t < 128) {
    const int g = t >> 3, l = t & 7;          // g: 0..7 Cb, 8..15 Cr
    float* plane = (g & 8) ? &Crp[0][0] : &Cbp[0][0];
    float* rowp = plane + l*68 + (g & 7)*8;
    float4 L0 = *(const float4*)&rowp[0];
    float4 L1 = *(const float4*)&rowp[4];
    float v[8] = {L0.x, L0.y, L0.z, L0.w, L1.x, L1.y, L1.z, L1.w};
    jblk8(v, l, &Scr[g][0], &QTs[1][l][0], &RQs[1][l][0]);  // chroma table
    *(float4*)&rowp[0] = make_float4(v[0],v[1],v[2],v[3]);
    *(float4*)&rowp[4] = make_float4(v[4],v[5],v[6],v[7]);
  }
  __syncthreads();

  // ---------------- output: upsample chroma, YCbCr->RGB, round/clip.
  // /255 after rintf carries no rounding decision -> multiply (R8-proven).
  {
    float4 Y0 = *(const float4*)&Yp[2*pr+0][4*pc];
    float4 Y1 = *(const float4*)&Yp[2*pr+1][4*pc];
    float y0[4] = {Y0.x, Y0.y, Y0.z, Y0.w};
    float y1[4] = {Y1.x, Y1.y, Y1.z, Y1.w};
    float2 cbp2 = *(const float2*)&Cbp[pr][2*pc];
    float2 crp2 = *(const float2*)&Crp[pr][2*pc];
    float cbq[2] = {cbp2.x, cbp2.y};
    float crq[2] = {crp2.x, crp2.y};
    #pragma unroll
    for (int rr = 0; rr < 2; ++rr) {
      float ov[12];
      #pragma unroll
      for (int p = 0; p < 4; ++p) {
        float y2  = (rr ? y1[p] : y0[p]) + 128.0f;
        float cb2 = cbq[p>>1] + 128.0f;
        float cr2 = crq[p>>1] + 128.0f;
        float r2 = y2 + 1.402f*(cr2 - 128.0f);
        float g2 = y2 - 0.344136f*(cb2 - 128.0f) - 0.714136f*(cr2 - 128.0f);
        float b2 = y2 + 1.772f*(cb2 - 128.0f);
        ov[3*p+0] = rintf(fminf(fmaxf(r2, 0.0f), 255.0f)) * C255;
        ov[3*p+1] = rintf(fminf(fmaxf(g2, 0.0f), 255.0f)) * C255;
        ov[3*p+2] = rintf(fminf(fmaxf(b2, 0.0f), 255.0f)) * C255;
      }
      const size_t grow = (size_t)img * 512 + (size_t)(ty*16 + 2*pr + rr);
      float* op = out + (grow*512 + (size_t)(tx*128 + 4*pc))*3;
      ((float4*)op)[0] = make_float4(ov[0],ov[1],ov[2],ov[3]);
      ((float4*)op)[1] = make_float4(ov[4],ov[5],ov[6],ov[7]);
      ((float4*)op)[2] = make_float4(ov[8],ov[9],ov[10],ov[11]);
    }
  }
}

extern "C" void kernel_launch(void* const* d_in, const int* in_sizes, int n_in,
                              void* d_out, int out_size, void* d_ws, size_t ws_size,
                              hipStream_t stream) {
  (void)in_sizes; (void)n_in; (void)d_ws; (void)ws_size; (void)out_size;
  const float* x = (const float*)d_in[0];
  float* out = (float*)d_out;
  dim3 grid(4, 32, 32);   // W/128, H/16, B
  jpeg_rt<<<grid, dim3(256), 0, stream>>>(x, out);
}